// Round 4
// baseline (400.842 us; speedup 1.0000x reference)
//
#include <hip/hip_runtime.h>
#include <hip/hip_bf16.h>

typedef __attribute__((ext_vector_type(4))) float f32x4;
typedef __attribute__((ext_vector_type(8))) short bf16x8;
typedef __attribute__((ext_vector_type(8))) unsigned short u16x8;

#define NN 8192
#define SK 8
#define KSL (NN / SK)      // 1024 k per WG
#define NSTEP (KSL / 32)   // 32 k-steps

__device__ __forceinline__ unsigned short f2bf(float f) {
    unsigned int u = __float_as_uint(f);
    u += 0x7fffu + ((u >> 16) & 1u);
    return (unsigned short)(u >> 16);
}

__global__ __launch_bounds__(256) void prep_v(const float* __restrict__ La,
        const float* __restrict__ ve, const float* __restrict__ ve2,
        float* __restrict__ V1, float* __restrict__ V2) {
    int i = blockIdx.x * 256 + threadIdx.x;
    float la = La[i];
    V1[i] = powf(la, ve[0]);
    float b = 2.0f * (la - 1e-8f) - 1.0f;
    V2[i] = powf(b * b + 1.0f, ve2[0]);
}

// C[i][j] = sum_k A(i,k)*B(k,j); A(i,k) = TRANS ? U[k][i] : U[i][k] (U f32).
// B supplied transposed: Bt bf16 [64][NN], Bt[j][k] = B[k][j].
// Output: P[sk][i][j] f32 partials. BM=64, 4 waves each own 16 rows.
// Barrier-free k-loop, 1-step register prefetch of A and B.
template<int TRANS>
__global__ __launch_bounds__(256, 4) void gemm_pass(const float* __restrict__ U,
        const unsigned short* __restrict__ Bt, float* __restrict__ P) {
    const int tid = threadIdx.x;
    const int w = tid >> 6, l = tid & 63;
    const int lm = l & 15, g = l >> 4;
    const int i0 = blockIdx.x * 64;
    const int kbase = blockIdx.y * KSL;
    const int m = i0 + w * 16 + lm;

    f32x4 acc[4];
#pragma unroll
    for (int nf = 0; nf < 4; ++nf) acc[nf] = (f32x4)0.f;

    const unsigned short* bp0 = Bt + (size_t)lm * NN + kbase + 8 * g;

    // A base pointers
    const float* apn = U + (size_t)m * NN + kbase + 8 * g;            // non-T
    const float* apt = U + (size_t)(kbase + 8 * g) * NN + m;          // T

    // ---- preload step 0 ----
    f32x4 a0, a1;
    float s0, s1, s2, s3, s4, s5, s6, s7;
    if (!TRANS) {
        a0 = *(const f32x4*)(apn + 0);
        a1 = *(const f32x4*)(apn + 4);
    } else {
        s0 = apt[0 * (size_t)NN]; s1 = apt[1 * (size_t)NN];
        s2 = apt[2 * (size_t)NN]; s3 = apt[3 * (size_t)NN];
        s4 = apt[4 * (size_t)NN]; s5 = apt[5 * (size_t)NN];
        s6 = apt[6 * (size_t)NN]; s7 = apt[7 * (size_t)NN];
    }
    bf16x8 b0 = *(const bf16x8*)(bp0);
    bf16x8 b1 = *(const bf16x8*)(bp0 + 16 * (size_t)NN);
    bf16x8 b2 = *(const bf16x8*)(bp0 + 32 * (size_t)NN);
    bf16x8 b3 = *(const bf16x8*)(bp0 + 48 * (size_t)NN);

#pragma unroll 2
    for (int t = 0; t < NSTEP; ++t) {
        // ---- prefetch step t+1 (stays in flight through this step's MFMAs) ----
        f32x4 na0, na1;
        float n0, n1, n2, n3, n4, n5, n6, n7;
        bf16x8 nb0, nb1, nb2, nb3;
        if (t + 1 < NSTEP) {
            const int ko = (t + 1) * 32;
            if (!TRANS) {
                na0 = *(const f32x4*)(apn + ko);
                na1 = *(const f32x4*)(apn + ko + 4);
            } else {
                const float* p = apt + (size_t)ko * NN;
                n0 = p[0 * (size_t)NN]; n1 = p[1 * (size_t)NN];
                n2 = p[2 * (size_t)NN]; n3 = p[3 * (size_t)NN];
                n4 = p[4 * (size_t)NN]; n5 = p[5 * (size_t)NN];
                n6 = p[6 * (size_t)NN]; n7 = p[7 * (size_t)NN];
            }
            nb0 = *(const bf16x8*)(bp0 + ko);
            nb1 = *(const bf16x8*)(bp0 + 16 * (size_t)NN + ko);
            nb2 = *(const bf16x8*)(bp0 + 32 * (size_t)NN + ko);
            nb3 = *(const bf16x8*)(bp0 + 48 * (size_t)NN + ko);
        }
        // ---- convert current A ----
        bf16x8 afr;
        if (!TRANS) {
#pragma unroll
            for (int j = 0; j < 4; ++j) {
                afr[j]     = (short)f2bf(a0[j]);
                afr[4 + j] = (short)f2bf(a1[j]);
            }
        } else {
            afr[0] = (short)f2bf(s0); afr[1] = (short)f2bf(s1);
            afr[2] = (short)f2bf(s2); afr[3] = (short)f2bf(s3);
            afr[4] = (short)f2bf(s4); afr[5] = (short)f2bf(s5);
            afr[6] = (short)f2bf(s6); afr[7] = (short)f2bf(s7);
        }
        acc[0] = __builtin_amdgcn_mfma_f32_16x16x32_bf16(afr, b0, acc[0], 0, 0, 0);
        acc[1] = __builtin_amdgcn_mfma_f32_16x16x32_bf16(afr, b1, acc[1], 0, 0, 0);
        acc[2] = __builtin_amdgcn_mfma_f32_16x16x32_bf16(afr, b2, acc[2], 0, 0, 0);
        acc[3] = __builtin_amdgcn_mfma_f32_16x16x32_bf16(afr, b3, acc[3], 0, 0, 0);
        // ---- rotate ----
        if (t + 1 < NSTEP) {
            a0 = na0; a1 = na1;
            s0 = n0; s1 = n1; s2 = n2; s3 = n3;
            s4 = n4; s5 = n5; s6 = n6; s7 = n7;
            b0 = nb0; b1 = nb1; b2 = nb2; b3 = nb3;
        }
    }
    float* Pp = P + (size_t)blockIdx.y * NN * 64;
#pragma unroll
    for (int nf = 0; nf < 4; ++nf)
#pragma unroll
        for (int r = 0; r < 4; ++r)
            Pp[(size_t)(i0 + w * 16 + 4 * g + r) * 64 + nf * 16 + lm] = acc[nf][r];
}

// Bt[j][i] = bf16( (V ? V[i] : 1) * sum_sk P[sk][i][j] ), P shape [nsk][NN][64]
// 256 WGs, 32 rows each.
__global__ __launch_bounds__(256) void reduce_t(const float* __restrict__ P, int nsk,
        const float* __restrict__ V, unsigned short* __restrict__ Bt) {
    __shared__ float T[32][65];
    int i0 = blockIdx.x * 32;
    int tid = threadIdx.x;
    int il = tid >> 3, jq = (tid & 7) * 8;
    f32x4 s0 = (f32x4)0.f, s1 = (f32x4)0.f;
    for (int k = 0; k < nsk; ++k) {
        const float* p = P + ((size_t)k * NN + i0 + il) * 64 + jq;
        s0 += *(const f32x4*)p;
        s1 += *(const f32x4*)(p + 4);
    }
    float sc = V ? V[i0 + il] : 1.0f;
#pragma unroll
    for (int c = 0; c < 4; ++c) {
        T[il][jq + c] = s0[c] * sc;
        T[il][jq + 4 + c] = s1[c] * sc;
    }
    __syncthreads();
    int j = tid >> 2, iq = (tid & 3) * 8;
    u16x8 o;
#pragma unroll
    for (int c = 0; c < 8; ++c) o[c] = f2bf(T[iq + c][j]);
    *(u16x8*)(Bt + (size_t)j * NN + i0 + iq) = o;
}

// Z2 = sum of partials; hidden = Z2 @ Ww^T + Wb; also per-block BN partial sums.
__global__ __launch_bounds__(256) void reduce_linear(const float* __restrict__ P,
        const float* __restrict__ Ww, const float* __restrict__ Wb,
        float* __restrict__ hidden, float* __restrict__ bsum, float* __restrict__ bsq) {
    __shared__ float z[32][65];
    __shared__ float w[64][65];
    __shared__ float hl[32][65];
    int i0 = blockIdx.x * 32;
    int tid = threadIdx.x;
    for (int e = tid * 4; e < 4096; e += 1024) {
        f32x4 v = *(const f32x4*)(Ww + e);
        int h = e >> 6, c = e & 63;
#pragma unroll
        for (int q = 0; q < 4; ++q) w[h][c + q] = v[q];
    }
    int r = tid >> 3, c8 = (tid & 7) * 8;
    f32x4 a0 = (f32x4)0.f, a1 = (f32x4)0.f;
    for (int k = 0; k < SK; ++k) {
        const float* p = P + ((size_t)k * NN + i0 + r) * 64 + c8;
        a0 += *(const f32x4*)p;
        a1 += *(const f32x4*)(p + 4);
    }
#pragma unroll
    for (int q = 0; q < 4; ++q) { z[r][c8 + q] = a0[q]; z[r][c8 + 4 + q] = a1[q]; }
    __syncthreads();
    int h8 = (tid & 7) * 8;
#pragma unroll
    for (int hh = 0; hh < 8; ++hh) {
        int h = h8 + hh;
        float s = Wb[h];
        for (int c = 0; c < 64; ++c) s += z[r][c] * w[h][c];
        hidden[(size_t)(i0 + r) * 64 + h] = s;
        hl[r][h] = s;
    }
    __syncthreads();
    if (tid < 64) {
        float s = 0.f, q2 = 0.f;
#pragma unroll
        for (int rr = 0; rr < 32; ++rr) {
            float v = hl[rr][tid];
            s += v; q2 += v * v;
        }
        bsum[blockIdx.x * 64 + tid] = s;
        bsq[blockIdx.x * 64 + tid] = q2;
    }
}

__global__ __launch_bounds__(64) void bn_stats(const float* __restrict__ bsum,
        const float* __restrict__ bsq, const float* __restrict__ gamma,
        const float* __restrict__ beta, float* __restrict__ bnc) {
    int h = threadIdx.x;
    float s = 0.f, q = 0.f;
    for (int b = 0; b < 256; ++b) { s += bsum[b * 64 + h]; q += bsq[b * 64 + h]; }
    float mean = s / 8192.0f;
    float var = q / 8192.0f - mean * mean;
    float inv = rsqrtf(var + 1e-5f);
    float sc = gamma[h] * inv;
    bnc[h] = sc;
    bnc[64 + h] = beta[h] - mean * sc;
}

__global__ __launch_bounds__(256) void head(const float* __restrict__ hidden,
        const float* __restrict__ bnc, const float* __restrict__ Mw,
        const float* __restrict__ Mb, float* __restrict__ out0) {
    __shared__ float a[32][65];
    __shared__ float w[32][65];
    __shared__ float o[32][33];
    __shared__ float rowm[32];
    int i0 = blockIdx.x * 32;
    int tid = threadIdx.x;
    for (int e = tid * 4; e < 2048; e += 1024) {
        f32x4 v = *(const f32x4*)(Mw + e);
        int oo = e >> 6, c = e & 63;
#pragma unroll
        for (int q = 0; q < 4; ++q) w[oo][c + q] = v[q];
    }
    int r = tid >> 3, h8 = (tid & 7) * 8;
    const float* hp = hidden + (size_t)(i0 + r) * 64 + h8;
#pragma unroll
    for (int q = 0; q < 8; ++q) {
        int h = h8 + q;
        float v = hp[q] * bnc[h] + bnc[64 + h];
        a[r][h] = fmaxf(v, 0.f);
    }
    __syncthreads();
    int o4 = (tid & 7) * 4;
#pragma unroll
    for (int q = 0; q < 4; ++q) {
        int oo = o4 + q;
        float s = Mb[oo];
        for (int c = 0; c < 64; ++c) s += a[r][c] * w[oo][c];
        o[r][oo] = s;
    }
    __syncthreads();
    if (tid < 32) {
        float m = -3.0e38f;
#pragma unroll
        for (int c = 0; c < 32; ++c) m = fmaxf(m, o[tid][c]);
        float se = 0.f;
#pragma unroll
        for (int c = 0; c < 32; ++c) se += expf(o[tid][c] - m);
        rowm[tid] = m + logf(se);
    }
    __syncthreads();
    f32x4 v;
#pragma unroll
    for (int q = 0; q < 4; ++q) v[q] = o[r][o4 + q] - rowm[r];
    *(f32x4*)(out0 + (size_t)(i0 + r) * 32 + o4) = v;
}

extern "C" void kernel_launch(void* const* d_in, const int* in_sizes, int n_in,
                              void* d_out, int out_size, void* d_ws, size_t ws_size,
                              hipStream_t stream) {
    const float* X   = (const float*)d_in[0];
    const float* La  = (const float*)d_in[1];
    const float* U   = (const float*)d_in[2];
    const float* ve  = (const float*)d_in[3];
    const float* ve2 = (const float*)d_in[4];
    const float* Ww  = (const float*)d_in[5];
    const float* Wb  = (const float*)d_in[6];
    const float* gam = (const float*)d_in[7];
    const float* bet = (const float*)d_in[8];
    const float* Mw  = (const float*)d_in[9];
    const float* Mb  = (const float*)d_in[10];
    float* out0 = (float*)d_out;
    float* hidden = (float*)d_out + (size_t)NN * 32;   // output 1 region

    char* ws = (char*)d_ws;
    float* V1   = (float*)ws;                             // 32 KB
    float* V2   = (float*)(ws + 32768);                   // 32 KB
    float* bsum = (float*)(ws + 65536);                   // 64 KB
    float* bsq  = (float*)(ws + 131072);                  // 64 KB
    float* bnc  = (float*)(ws + 196608);                  // 512 B
    unsigned short* Bt = (unsigned short*)(ws + 262144);  // 1 MB bf16 [64][NN]
    float* P    = (float*)(ws + (2u << 20));              // 16 MB partials [SK][NN][64]

    prep_v<<<32, 256, 0, stream>>>(La, ve, ve2, V1, V2);
    // Bt = X^T
    reduce_t<<<256, 256, 0, stream>>>(X, 1, nullptr, Bt);
    // T1 = U^T @ X
    gemm_pass<1><<<dim3(NN / 64, SK), 256, 0, stream>>>(U, Bt, P);
    // Bt = (V1 * T1)^T
    reduce_t<<<256, 256, 0, stream>>>(P, SK, V1, Bt);
    // Z1 = U @ S1
    gemm_pass<0><<<dim3(NN / 64, SK), 256, 0, stream>>>(U, Bt, P);
    reduce_t<<<256, 256, 0, stream>>>(P, SK, nullptr, Bt);
    // T2 = U^T @ Z1
    gemm_pass<1><<<dim3(NN / 64, SK), 256, 0, stream>>>(U, Bt, P);
    // Bt = (V2 * T2)^T
    reduce_t<<<256, 256, 0, stream>>>(P, SK, V2, Bt);
    // Z2 = U @ S2
    gemm_pass<0><<<dim3(NN / 64, SK), 256, 0, stream>>>(U, Bt, P);
    // hidden = Z2 @ Ww^T + Wb  (+ BN partial stats)
    reduce_linear<<<256, 256, 0, stream>>>(P, Ww, Wb, hidden, bsum, bsq);
    bn_stats<<<1, 64, 0, stream>>>(bsum, bsq, gam, bet, bnc);
    head<<<256, 256, 0, stream>>>(hidden, bnc, Mw, Mb, out0);
}

// Round 5
// 293.011 us; speedup vs baseline: 1.3680x; 1.3680x over previous
//
#include <hip/hip_runtime.h>
#include <hip/hip_bf16.h>

typedef __attribute__((ext_vector_type(4))) float f32x4;
typedef __attribute__((ext_vector_type(8))) short bf16x8;
typedef __attribute__((ext_vector_type(8))) unsigned short u16x8;

#define NN 8192
#define SK 8
#define KSL (NN / SK)      // 1024 k per WG
#define NC (KSL / 64)      // 16 chunks of 64 k

__device__ __forceinline__ unsigned short f2bf(float f) {
    unsigned int u = __float_as_uint(f);
    u += 0x7fffu + ((u >> 16) & 1u);
    return (unsigned short)(u >> 16);
}

__global__ __launch_bounds__(256) void prep_v(const float* __restrict__ La,
        const float* __restrict__ ve, const float* __restrict__ ve2,
        float* __restrict__ V1, float* __restrict__ V2) {
    int i = blockIdx.x * 256 + threadIdx.x;
    float la = La[i];
    V1[i] = powf(la, ve[0]);
    float b = 2.0f * (la - 1e-8f) - 1.0f;
    V2[i] = powf(b * b + 1.0f, ve2[0]);
}

// ---------------------------------------------------------------------------
// Frag-major B layout: FB[((t*4+nf)*64 + l)*8 + s] = B[k][j]*scale,
//   k = 32t + 8*(l>>4) + s,  j = 16nf + (l&15).
// gemm: C[i][j] = sum_k A(i,k)*B(k,j); A(i,k) = TRANS ? U[k][i] : U[i][k].
// BM=64 (4 waves x 16 rows), chunk=64k, wave-private LDS staging (no barriers),
// straight-line ping-pong so all vmcnt waits are counted.
// ---------------------------------------------------------------------------
template<int TRANS>
__global__ __launch_bounds__(256, 4) void gemm_pass(const float* __restrict__ U,
        const unsigned short* __restrict__ FB, float* __restrict__ P) {
    __shared__ float lds[4 * 1152];
    const int tid = threadIdx.x;
    const int w = tid >> 6, l = tid & 63;
    const int lm = l & 15, g = l >> 4;
    const int i0 = blockIdx.x * 64;
    const int kbase = blockIdx.y * KSL;
    const int m0 = i0 + w * 16;

    float* wlds = lds + w * 1152;

    // coalesced staging addresses (16 line-touches per f32x4 instr)
    const float* gbase = TRANS
        ? U + (size_t)(kbase + (l >> 2)) * NN + m0 + (l & 3) * 4
        : U + (size_t)(m0 + (l >> 2)) * NN + kbase + (l & 3) * 16;
    float* wptr = TRANS ? (wlds + 4 * l) : (wlds + (l >> 2) * 68 + (l & 3) * 16);

    const unsigned short* fbb =
        FB + ((size_t)(blockIdx.y * (KSL / 32)) * 4 * 64 + l) * 8;

    f32x4 acc[4];
#pragma unroll
    for (int nf = 0; nf < 4; ++nf) acc[nf] = (f32x4)0.f;

    f32x4 ra0[4], ra1[4];

#define ISSUE_A(r, c)                                                          \
    do {                                                                       \
        if (TRANS) {                                                           \
            const float* p_ = gbase + (size_t)(64 * (c)) * NN;                 \
            r[0] = *(const f32x4*)(p_);                                        \
            r[1] = *(const f32x4*)(p_ + (size_t)16 * NN);                      \
            r[2] = *(const f32x4*)(p_ + (size_t)32 * NN);                      \
            r[3] = *(const f32x4*)(p_ + (size_t)48 * NN);                      \
        } else {                                                               \
            const float* p_ = gbase + 64 * (c);                                \
            r[0] = *(const f32x4*)(p_);                                        \
            r[1] = *(const f32x4*)(p_ + 4);                                    \
            r[2] = *(const f32x4*)(p_ + 8);                                    \
            r[3] = *(const f32x4*)(p_ + 12);                                   \
        }                                                                      \
    } while (0)

#define ISSUE_B(bf, c)                                                         \
    do {                                                                       \
        _Pragma("unroll")                                                      \
        for (int sp_ = 0; sp_ < 2; ++sp_)                                      \
            _Pragma("unroll")                                                  \
            for (int nf_ = 0; nf_ < 4; ++nf_)                                  \
                bf[sp_ * 4 + nf_] = *(const bf16x8*)(fbb +                     \
                    (size_t)((2 * (c) + sp_) * 4 + nf_) * 512);                \
    } while (0)

#define DSW(r)                                                                 \
    do {                                                                       \
        if (TRANS) {                                                           \
            *(f32x4*)(wptr + 0)   = r[0];                                      \
            *(f32x4*)(wptr + 256) = r[1];                                      \
            *(f32x4*)(wptr + 512) = r[2];                                      \
            *(f32x4*)(wptr + 768) = r[3];                                      \
        } else {                                                               \
            *(f32x4*)(wptr + 0)  = r[0];                                       \
            *(f32x4*)(wptr + 4)  = r[1];                                       \
            *(f32x4*)(wptr + 8)  = r[2];                                       \
            *(f32x4*)(wptr + 12) = r[3];                                       \
        }                                                                      \
    } while (0)

#define COMP(bf)                                                               \
    do {                                                                       \
        _Pragma("unroll")                                                      \
        for (int sp_ = 0; sp_ < 2; ++sp_) {                                    \
            bf16x8 afr_;                                                       \
            if (TRANS) {                                                       \
                const float* rp_ = wlds + (32 * sp_ + 8 * g) * 16 + lm;        \
                _Pragma("unroll")                                              \
                for (int j_ = 0; j_ < 8; ++j_)                                 \
                    afr_[j_] = (short)f2bf(rp_[j_ * 16]);                      \
            } else {                                                           \
                const float* rp_ = wlds + lm * 68 + 32 * sp_ + 8 * g;          \
                f32x4 a0_ = *(const f32x4*)rp_;                                \
                f32x4 a1_ = *(const f32x4*)(rp_ + 4);                          \
                _Pragma("unroll")                                              \
                for (int j_ = 0; j_ < 4; ++j_) {                               \
                    afr_[j_]     = (short)f2bf(a0_[j_]);                       \
                    afr_[4 + j_] = (short)f2bf(a1_[j_]);                       \
                }                                                              \
            }                                                                  \
            _Pragma("unroll")                                                  \
            for (int nf_ = 0; nf_ < 4; ++nf_)                                  \
                acc[nf_] = __builtin_amdgcn_mfma_f32_16x16x32_bf16(            \
                    afr_, bf[sp_ * 4 + nf_], acc[nf_], 0, 0, 0);               \
        }                                                                      \
    } while (0)

    ISSUE_A(ra0, 0);
#pragma unroll
    for (int c = 0; c < NC; c += 2) {
        {
            bf16x8 bf[8];
            ISSUE_B(bf, c);
            if (c + 1 < NC) ISSUE_A(ra1, c + 1);
            DSW(ra0);
            COMP(bf);
        }
        {
            bf16x8 bf[8];
            ISSUE_B(bf, c + 1);
            if (c + 2 < NC) ISSUE_A(ra0, c + 2);
            DSW(ra1);
            COMP(bf);
        }
    }
#undef ISSUE_A
#undef ISSUE_B
#undef DSW
#undef COMP

    float* Pp = P + (size_t)blockIdx.y * NN * 64;
#pragma unroll
    for (int nf = 0; nf < 4; ++nf)
#pragma unroll
        for (int r = 0; r < 4; ++r)
            Pp[(size_t)(m0 + 4 * g + r) * 64 + nf * 16 + lm] = acc[nf][r];
}

// ---------------------------------------------------------------------------
// FB[((b*4+nf)*64 + l)*8 + s] = bf16( scale(i) * sum_sk M[sk][i][j] ),
//   i = 32b + 8*(l>>4) + s, j = 16nf + (l&15).  M: [nsk][NN][64] (or X, nsk=1)
// ---------------------------------------------------------------------------
__global__ __launch_bounds__(256) void reduce_t(const float* __restrict__ M, int nsk,
        const float* __restrict__ V, unsigned short* __restrict__ FB) {
    __shared__ float T[32][65];
    int b = blockIdx.x;
    int i0 = b * 32;
    int tid = threadIdx.x;
    int il = tid >> 3, jq = (tid & 7) * 8;
    f32x4 s0 = (f32x4)0.f, s1 = (f32x4)0.f;
    for (int k = 0; k < nsk; ++k) {
        const float* p = M + ((size_t)k * NN + i0 + il) * 64 + jq;
        s0 += *(const f32x4*)p;
        s1 += *(const f32x4*)(p + 4);
    }
    float sc = V ? V[i0 + il] : 1.0f;
#pragma unroll
    for (int c = 0; c < 4; ++c) {
        T[il][jq + c] = s0[c] * sc;
        T[il][jq + 4 + c] = s1[c] * sc;
    }
    __syncthreads();
    int nf = tid >> 6, l = tid & 63, g = l >> 4, lm = l & 15;
    u16x8 o;
#pragma unroll
    for (int s = 0; s < 8; ++s) o[s] = f2bf(T[8 * g + s][16 * nf + lm]);
    *(u16x8*)(FB + ((size_t)(b * 4 + nf) * 64 + l) * 8) = o;
}

// Z2 = sum of partials; hidden = Z2 @ Ww^T + Wb; also per-block BN partial sums.
__global__ __launch_bounds__(256) void reduce_linear(const float* __restrict__ P,
        const float* __restrict__ Ww, const float* __restrict__ Wb,
        float* __restrict__ hidden, float* __restrict__ bsum, float* __restrict__ bsq) {
    __shared__ float z[32][65];
    __shared__ float w[64][65];
    __shared__ float hl[32][65];
    int i0 = blockIdx.x * 32;
    int tid = threadIdx.x;
    for (int e = tid * 4; e < 4096; e += 1024) {
        f32x4 v = *(const f32x4*)(Ww + e);
        int h = e >> 6, c = e & 63;
#pragma unroll
        for (int q = 0; q < 4; ++q) w[h][c + q] = v[q];
    }
    int r = tid >> 3, c8 = (tid & 7) * 8;
    f32x4 a0 = (f32x4)0.f, a1 = (f32x4)0.f;
    for (int k = 0; k < SK; ++k) {
        const float* p = P + ((size_t)k * NN + i0 + r) * 64 + c8;
        a0 += *(const f32x4*)p;
        a1 += *(const f32x4*)(p + 4);
    }
#pragma unroll
    for (int q = 0; q < 4; ++q) { z[r][c8 + q] = a0[q]; z[r][c8 + 4 + q] = a1[q]; }
    __syncthreads();
    int h8 = (tid & 7) * 8;
#pragma unroll
    for (int hh = 0; hh < 8; ++hh) {
        int h = h8 + hh;
        float s = Wb[h];
        for (int c = 0; c < 64; ++c) s += z[r][c] * w[h][c];
        hidden[(size_t)(i0 + r) * 64 + h] = s;
        hl[r][h] = s;
    }
    __syncthreads();
    if (tid < 64) {
        float s = 0.f, q2 = 0.f;
#pragma unroll
        for (int rr = 0; rr < 32; ++rr) {
            float v = hl[rr][tid];
            s += v; q2 += v * v;
        }
        bsum[blockIdx.x * 64 + tid] = s;
        bsq[blockIdx.x * 64 + tid] = q2;
    }
}

__global__ __launch_bounds__(64) void bn_stats(const float* __restrict__ bsum,
        const float* __restrict__ bsq, const float* __restrict__ gamma,
        const float* __restrict__ beta, float* __restrict__ bnc) {
    int h = threadIdx.x;
    float s = 0.f, q = 0.f;
    for (int b = 0; b < 256; ++b) { s += bsum[b * 64 + h]; q += bsq[b * 64 + h]; }
    float mean = s / 8192.0f;
    float var = q / 8192.0f - mean * mean;
    float inv = rsqrtf(var + 1e-5f);
    float sc = gamma[h] * inv;
    bnc[h] = sc;
    bnc[64 + h] = beta[h] - mean * sc;
}

__global__ __launch_bounds__(256) void head(const float* __restrict__ hidden,
        const float* __restrict__ bnc, const float* __restrict__ Mw,
        const float* __restrict__ Mb, float* __restrict__ out0) {
    __shared__ float a[32][65];
    __shared__ float w[32][65];
    __shared__ float o[32][33];
    __shared__ float rowm[32];
    int i0 = blockIdx.x * 32;
    int tid = threadIdx.x;
    for (int e = tid * 4; e < 2048; e += 1024) {
        f32x4 v = *(const f32x4*)(Mw + e);
        int oo = e >> 6, c = e & 63;
#pragma unroll
        for (int q = 0; q < 4; ++q) w[oo][c + q] = v[q];
    }
    int r = tid >> 3, h8 = (tid & 7) * 8;
    const float* hp = hidden + (size_t)(i0 + r) * 64 + h8;
#pragma unroll
    for (int q = 0; q < 8; ++q) {
        int h = h8 + q;
        float v = hp[q] * bnc[h] + bnc[64 + h];
        a[r][h] = fmaxf(v, 0.f);
    }
    __syncthreads();
    int o4 = (tid & 7) * 4;
#pragma unroll
    for (int q = 0; q < 4; ++q) {
        int oo = o4 + q;
        float s = Mb[oo];
        for (int c = 0; c < 64; ++c) s += a[r][c] * w[oo][c];
        o[r][oo] = s;
    }
    __syncthreads();
    if (tid < 32) {
        float m = -3.0e38f;
#pragma unroll
        for (int c = 0; c < 32; ++c) m = fmaxf(m, o[tid][c]);
        float se = 0.f;
#pragma unroll
        for (int c = 0; c < 32; ++c) se += expf(o[tid][c] - m);
        rowm[tid] = m + logf(se);
    }
    __syncthreads();
    f32x4 v;
#pragma unroll
    for (int q = 0; q < 4; ++q) v[q] = o[r][o4 + q] - rowm[r];
    *(f32x4*)(out0 + (size_t)(i0 + r) * 32 + o4) = v;
}

extern "C" void kernel_launch(void* const* d_in, const int* in_sizes, int n_in,
                              void* d_out, int out_size, void* d_ws, size_t ws_size,
                              hipStream_t stream) {
    const float* X   = (const float*)d_in[0];
    const float* La  = (const float*)d_in[1];
    const float* U   = (const float*)d_in[2];
    const float* ve  = (const float*)d_in[3];
    const float* ve2 = (const float*)d_in[4];
    const float* Ww  = (const float*)d_in[5];
    const float* Wb  = (const float*)d_in[6];
    const float* gam = (const float*)d_in[7];
    const float* bet = (const float*)d_in[8];
    const float* Mw  = (const float*)d_in[9];
    const float* Mb  = (const float*)d_in[10];
    float* out0 = (float*)d_out;
    float* hidden = (float*)d_out + (size_t)NN * 32;   // output 1 region

    char* ws = (char*)d_ws;
    float* V1   = (float*)ws;                             // 32 KB
    float* V2   = (float*)(ws + 32768);                   // 32 KB
    float* bsum = (float*)(ws + 65536);                   // 64 KB
    float* bsq  = (float*)(ws + 131072);                  // 64 KB
    float* bnc  = (float*)(ws + 196608);                  // 512 B
    unsigned short* FB = (unsigned short*)(ws + 262144);  // 1 MB bf16 frag-major
    float* P    = (float*)(ws + (2u << 20));              // 16 MB partials [SK][NN][64]

    prep_v<<<32, 256, 0, stream>>>(La, ve, ve2, V1, V2);
    // FB = frag(X)
    reduce_t<<<256, 256, 0, stream>>>(X, 1, nullptr, FB);
    // T1 = U^T @ X
    gemm_pass<1><<<dim3(NN / 64, SK), 256, 0, stream>>>(U, FB, P);
    // FB = frag(V1 * T1)
    reduce_t<<<256, 256, 0, stream>>>(P, SK, V1, FB);
    // Z1 = U @ S1
    gemm_pass<0><<<dim3(NN / 64, SK), 256, 0, stream>>>(U, FB, P);
    reduce_t<<<256, 256, 0, stream>>>(P, SK, nullptr, FB);
    // T2 = U^T @ Z1
    gemm_pass<1><<<dim3(NN / 64, SK), 256, 0, stream>>>(U, FB, P);
    // FB = frag(V2 * T2)
    reduce_t<<<256, 256, 0, stream>>>(P, SK, V2, FB);
    // Z2 = U @ S2
    gemm_pass<0><<<dim3(NN / 64, SK), 256, 0, stream>>>(U, FB, P);
    // hidden = Z2 @ Ww^T + Wb  (+ BN partial stats)
    reduce_linear<<<256, 256, 0, stream>>>(P, Ww, Wb, hidden, bsum, bsq);
    bn_stats<<<1, 64, 0, stream>>>(bsum, bsq, gam, bet, bnc);
    head<<<256, 256, 0, stream>>>(hidden, bnc, Mw, Mb, out0);
}